// Round 1
// 897.859 us; speedup vs baseline: 1.2694x; 1.2694x over previous
//
#include <hip/hip_runtime.h>

// PagedAttention fused pipeline for MI355X (gfx950).
// B=4 S=4096 HID=2048 H=16 P=256 D=128 N=16.
// Paged permutation (derived from flat strides of the unfold/reshape):
//   q/k/v:  heads[b,h,n*P+p,d] -> paged[x2=16b+h][h2=n][p2=2d+(p>>7)][d2=p&127]
//   output: ctx[x2][h2][p2][d3] -> out[b=x2>>4][s=256*(x2&15)+p2][c=128*h2+d3]
// GEMMs: 256x256 tile, BK=64, 8 waves (2x4), 8-phase schedule (T2+T3+T4+T5):
//   128KB double-buffered LDS, global_load_lds with inverse-swizzled source +
//   XOR-swizzled ds_read_b128 (chunk ^= row&7), counted vmcnt(4) at phases 4/8.

typedef unsigned short u16;
typedef unsigned int u32;
typedef __attribute__((ext_vector_type(8))) __bf16 bf16x8;
typedef __attribute__((ext_vector_type(4))) float f32x4;
typedef __attribute__((ext_vector_type(8))) u16 u16x8;

struct alignas(8) U4 { u16 x, y, z, w; };

#define SCALE_ 0.08838834764831845f

__device__ __forceinline__ u16 f2bf(float f) {
  union { float f; u32 u; } v; v.f = f;
  u32 r = v.u + 0x7fffu + ((v.u >> 16) & 1u);   // RNE
  return (u16)(r >> 16);
}

__device__ __forceinline__ void glds16(const void* g, void* l) {
  __builtin_amdgcn_global_load_lds(
      (const __attribute__((address_space(1))) u32*)g,
      (__attribute__((address_space(3))) u32*)l, 16, 0, 0);
}

// ---------------- fp32 -> bf16 conversion (vectorized x4) ----------------
__global__ void cvt_kernel(const float* __restrict__ src, u16* __restrict__ dst, int n4) {
  int i = blockIdx.x * 256 + threadIdx.x;
  if (i >= n4) return;
  float4 f = ((const float4*)src)[i];
  U4 o = { f2bf(f.x), f2bf(f.y), f2bf(f.z), f2bf(f.w) };
  ((U4*)dst)[i] = o;
}

// ---------------- GEMM: C[m,n] = sum_k A[m,k]*W[n,k] + bias[n] ----------------
// 256x256 tile, BK=64, 512 threads (8 waves as 2Mx4N, each owns 128x64 output).
// mode 0: write bf16 paged layout (Q/K).  mode 1: write bf16 transposed-paged (V).
// mode 2: write fp32 row-major (final output).

#define MFMA_Q(AF, BF, MB, NB) do { \
  _Pragma("unroll") for (int mt_ = 0; mt_ < 4; ++mt_) \
  _Pragma("unroll") for (int nt_ = 0; nt_ < 2; ++nt_) \
  _Pragma("unroll") for (int kh_ = 0; kh_ < 2; ++kh_) \
    acc[(MB)+mt_][(NB)+nt_] = __builtin_amdgcn_mfma_f32_16x16x32_bf16( \
      AF[mt_][kh_], BF[nt_][kh_], acc[(MB)+mt_][(NB)+nt_], 0, 0, 0); \
} while (0)

#define LDA(F, MTB, BUF) do { \
  _Pragma("unroll") for (int mt_ = 0; mt_ < 4; ++mt_) { \
    F[mt_][0] = *(const bf16x8*)(aRd0 + (BUF)*65536 + ((MTB)+mt_)*2048); \
    F[mt_][1] = *(const bf16x8*)(aRd1 + (BUF)*65536 + ((MTB)+mt_)*2048); \
  } } while (0)

#define LDB(F, NTB, BUF) do { \
  _Pragma("unroll") for (int nt_ = 0; nt_ < 2; ++nt_) { \
    F[nt_][0] = *(const bf16x8*)(bRd0 + (BUF)*65536 + ((NTB)+nt_)*2048); \
    F[nt_][1] = *(const bf16x8*)(bRd1 + (BUF)*65536 + ((NTB)+nt_)*2048); \
  } } while (0)

// A half-tile H (128 rows) of the k-tile starting at element KK into buffer BUF.
// LDS dest is linear (base + tid*16); global source column is inverse-swizzled
// (scs = cc ^ (row&7)) so that swizzled ds_reads see K-chunk c at slot c^(row&7).
#define STAGE_A(BUF, H, KK) do { \
  glds16(Asrc + (size_t)((H)*128) * 2048 + (KK), dstA + (BUF)*65536 + (H)*16384); \
  glds16(Asrc + (size_t)((H)*128 + 64) * 2048 + (KK), dstA + (BUF)*65536 + (H)*16384 + 8192); \
} while (0)

#define STAGE_B(BUF, H, KK) do { \
  glds16(Bsrc + (size_t)((H)*128) * 2048 + (KK), dstB + (BUF)*65536 + (H)*16384); \
  glds16(Bsrc + (size_t)((H)*128 + 64) * 2048 + (KK), dstB + (BUF)*65536 + (H)*16384 + 8192); \
} while (0)

#define PH_ENTER() do { \
  __builtin_amdgcn_s_barrier(); \
  asm volatile("s_waitcnt lgkmcnt(0)" ::: "memory"); \
  __builtin_amdgcn_sched_barrier(0); \
  __builtin_amdgcn_s_setprio(1); \
} while (0)

#define PH_EXIT() do { \
  __builtin_amdgcn_s_setprio(0); \
  __builtin_amdgcn_sched_barrier(0); \
  __builtin_amdgcn_s_barrier(); \
} while (0)

#define PH_EXIT_VM(N) do { \
  __builtin_amdgcn_s_setprio(0); \
  __builtin_amdgcn_sched_barrier(0); \
  asm volatile("s_waitcnt vmcnt(" #N ")" ::: "memory"); \
  __builtin_amdgcn_s_barrier(); \
} while (0)

#define LGKM_HINT() asm volatile("s_waitcnt lgkmcnt(8)" ::: "memory")

__global__ __launch_bounds__(512, 2) void gemm_kernel(
    const u16* __restrict__ A, const u16* __restrict__ Bw,
    const float* __restrict__ bias, void* __restrict__ outp, int mode)
{
  extern __shared__ char Sm[];                 // 131072: buf{0,1} x {A:32KB, B:32KB}
  const int tid  = threadIdx.x;
  const int lane = tid & 63;
  const int wid  = tid >> 6;
  const int L    = lane & 15;
  const int quad = lane >> 4;
  const int wm   = wid >> 2;                   // 0..1
  const int wn   = wid & 3;                    // 0..3
  // n-tile bound to XCD (bid&7): each XCD's L2 keeps one 1MB B-panel, reused 64x.
  const int m0 = (int)(blockIdx.x >> 3) << 8;
  const int n0 = (int)(blockIdx.x & 7) << 8;

  // staging: thread covers LDS chunk u=tid (and u=tid+512) of each half-tile.
  const int srow = tid >> 3;                   // 0..63 (row within 64-row stripe)
  const int scs  = (tid & 7) ^ (srow & 7);     // inverse-swizzled source chunk
  const u16* Asrc = A  + (size_t)(m0 + srow) * 2048 + scs * 8;
  const u16* Bsrc = Bw + (size_t)(n0 + srow) * 2048 + scs * 8;
  char* dstA = Sm + tid * 16;
  char* dstB = Sm + 32768 + tid * 16;

  // fragment read bases: row = (wm*128|wn*64) + <t>*16 + L, chunk (kh*4+quad)^(L&7)
  const int xA = ((quad ^ (L & 7)) << 4);
  const char* aRd0 = Sm + (wm * 128 + L) * 128 + xA;
  const char* aRd1 = Sm + (wm * 128 + L) * 128 + (xA ^ 64);
  const char* bRd0 = Sm + 32768 + (wn * 64 + L) * 128 + xA;
  const char* bRd1 = Sm + 32768 + (wn * 64 + L) * 128 + (xA ^ 64);

  f32x4 acc[8][4];
#pragma unroll
  for (int i = 0; i < 8; ++i)
#pragma unroll
    for (int j = 0; j < 4; ++j)
      acc[i][j] = f32x4{0.f, 0.f, 0.f, 0.f};

  bf16x8 aLo[4][2], aHi[4][2], bLo[2][2], bHi[2][2];

  // Prologue: buf0 <- tile0 (4 half-tiles), buf1 <- tile1 A halves.
  STAGE_A(0, 0, 0);
  STAGE_A(0, 1, 0);
  STAGE_B(0, 0, 0);
  STAGE_B(0, 1, 0);
  STAGE_A(1, 0, 64);
  STAGE_A(1, 1, 64);
  asm volatile("s_waitcnt vmcnt(4)" ::: "memory");   // tile0 landed; tile1.A in flight
  __builtin_amdgcn_s_barrier();

  // 16 iterations x 2 k-tiles (buf0: tile 2it, buf1: tile 2it+1).
  // Issue map: P1,P2 -> tile 2it+1 B0,B1 | P3..P6 -> tile 2it+2 A0,A1,B0,B1 |
  //            P7,P8 -> tile 2it+3 A0,A1.  vmcnt(4) at P4/P8 gates buffer reads.
#pragma unroll 1
  for (int it = 0; it < 16; ++it) {
    const int kb = it * 128;
    // ---- P1 ----
    LDA(aLo, 0, 0); LDB(bLo, 0, 0);
    STAGE_B(1, 0, kb + 64);
    LGKM_HINT();
    PH_ENTER();
    MFMA_Q(aLo, bLo, 0, 0);
    PH_EXIT();
    // ---- P2 ----
    LDA(aHi, 4, 0); LDB(bHi, 2, 0);
    STAGE_B(1, 1, kb + 64);
    LGKM_HINT();
    PH_ENTER();
    MFMA_Q(aLo, bHi, 0, 2);
    PH_EXIT();
    // ---- P3 ---- (buf0 fully consumed by ds_reads above; restage it)
    if (it < 15) STAGE_A(0, 0, kb + 128);
    PH_ENTER();
    MFMA_Q(aHi, bLo, 4, 0);
    PH_EXIT();
    // ---- P4 ----
    if (it < 15) STAGE_A(0, 1, kb + 128);
    PH_ENTER();
    MFMA_Q(aHi, bHi, 4, 2);
    if (it < 15) { PH_EXIT_VM(4); } else { PH_EXIT_VM(0); }  // buf1 writes landed
    // ---- P5 ----
    LDA(aLo, 0, 1); LDB(bLo, 0, 1);
    if (it < 15) STAGE_B(0, 0, kb + 128);
    LGKM_HINT();
    PH_ENTER();
    MFMA_Q(aLo, bLo, 0, 0);
    PH_EXIT();
    // ---- P6 ----
    LDA(aHi, 4, 1); LDB(bHi, 2, 1);
    if (it < 15) STAGE_B(0, 1, kb + 128);
    LGKM_HINT();
    PH_ENTER();
    MFMA_Q(aLo, bHi, 0, 2);
    PH_EXIT();
    // ---- P7 ---- (buf1 fully consumed; restage it)
    if (it < 15) STAGE_A(1, 0, kb + 192);
    PH_ENTER();
    MFMA_Q(aHi, bLo, 4, 0);
    PH_EXIT();
    // ---- P8 ----
    if (it < 15) STAGE_A(1, 1, kb + 192);
    PH_ENTER();
    MFMA_Q(aHi, bHi, 4, 2);
    PH_EXIT_VM(4);                                            // buf0 writes landed
  }

  // Epilogue. C frag: col = lane&15 (n), rows = quad*4 + reg (m).
#pragma unroll
  for (int nt = 0; nt < 4; ++nt) {
    const int c = n0 + wn * 64 + nt * 16 + L;
    const float bv = bias[c];
    const int h = c >> 7, d = c & 127;
#pragma unroll
    for (int mt = 0; mt < 8; ++mt) {
      const int sg = m0 + wm * 128 + mt * 16 + (quad << 2);   // global row in (B*S)
      const int b   = sg >> 12;
      const int s   = sg & 4095;
      const int npg = (s >> 8) & 15;
      const int half = (s >> 7) & 1;
      const int plo  = s & 127;                 // consecutive for the 4 regs
      const f32x4 v = acc[mt][nt];
      const size_t bb = ((size_t)((b * 16 + h) * 16 + npg)) << 15;  // *32768
      if (mode == 0) {
        U4 o = { f2bf(v[0] + bv), f2bf(v[1] + bv), f2bf(v[2] + bv), f2bf(v[3] + bv) };
        *(U4*)((u16*)outp + bb + (size_t)(2 * d + half) * 128 + plo) = o;
      } else if (mode == 1) {
        u16* o16 = (u16*)outp + bb + 2 * d + half;
        o16[(size_t)(plo + 0) * 256] = f2bf(v[0] + bv);
        o16[(size_t)(plo + 1) * 256] = f2bf(v[1] + bv);
        o16[(size_t)(plo + 2) * 256] = f2bf(v[2] + bv);
        o16[(size_t)(plo + 3) * 256] = f2bf(v[3] + bv);
      } else {
        float* of = (float*)outp + (size_t)sg * 2048 + c;
        of[0]    = v[0] + bv;
        of[2048] = v[1] + bv;
        of[4096] = v[2] + bv;
        of[6144] = v[3] + bv;
      }
    }
  }
}

// ---------------- Attention: one block (1024 thr, 16 waves) per page ----------------
// Stage K (64KB) into LDS with XOR-swizzled 16B-chunk placement (conflict-free
// fragment reads), compute S^T = K*Q^T, softmax in-register, then reuse the LDS
// for V and compute ctx^T = V^T * P^T (P^T B-frags built by shuffles).
__global__ __launch_bounds__(1024, 4) void attn_kernel(
    const u16* __restrict__ Qp, const u16* __restrict__ Kp,
    const u16* __restrict__ Vt, u16* __restrict__ ctx)
{
  __shared__ u16 Sm[32768];                    // 64 KB, holds K then V
  const int tid  = threadIdx.x;
  const int wid  = tid >> 6;
  const int lane = tid & 63;
  const int L    = lane & 15;
  const int quad = lane >> 4;
  const int pg   = blockIdx.x;                 // page = x2*16 + h2
  const int x2 = pg >> 4, h2 = pg & 15;
  const int q0 = wid * 16;                     // 16 queries per wave

  const char* Qb = (const char*)(Qp + (size_t)pg * 32768);
  const char* Kb = (const char*)(Kp + (size_t)pg * 32768);
  const char* Vb = (const char*)(Vt + (size_t)pg * 32768);

  // Stage K: LDS slot u (16B chunks): row=u>>4, cc=u&15; fetch global chunk
  // row*16 + (cc ^ (row&15)) so that K[row][c] lives at slot row*16 + (c^(row&15)).
#pragma unroll
  for (int r = 0; r < 4; ++r) {
    const int u = tid + (r << 10);
    const int row = u >> 4, cc = u & 15;
    glds16(Kb + (size_t)(row * 16 + (cc ^ (row & 15))) * 16, (char*)Sm + u * 16);
  }

  // Q B-frags: B[k=d][n=q], lane holds Q[q0+L][kt*32+quad*8+j] (row-contiguous)
  bf16x8 qf[4];
#pragma unroll
  for (int kt = 0; kt < 4; ++kt)
    qf[kt] = *(const bf16x8*)(Qb + (q0 + L) * 256 + kt * 64 + quad * 16);

  __syncthreads();

  // S^T accumulate: rows k2 (16 tiles), cols q (16). A = K rows from LDS.
  // Read K[row=mt*16+L][chunk c=kt*4+quad] at swizzled offset (c^L)*16.
  f32x4 st[16];
#pragma unroll
  for (int mt = 0; mt < 16; ++mt) st[mt] = f32x4{0.f, 0.f, 0.f, 0.f};
#pragma unroll
  for (int kt = 0; kt < 4; ++kt) {
    const int c = kt * 4 + quad;
#pragma unroll
    for (int mt = 0; mt < 16; ++mt) {
      bf16x8 a = *(const bf16x8*)((const char*)Sm + (mt * 16 + L) * 256 + ((c ^ L) << 4));
      st[mt] = __builtin_amdgcn_mfma_f32_16x16x32_bf16(a, qf[kt], st[mt], 0, 0, 0);
    }
  }

  // softmax over k2 for this lane's q (=L): 64 in-lane values + lanes {L,L+16,L+32,L+48}
  float mx = -3.0e38f;
#pragma unroll
  for (int mt = 0; mt < 16; ++mt) {
    mx = fmaxf(mx, st[mt][0]); mx = fmaxf(mx, st[mt][1]);
    mx = fmaxf(mx, st[mt][2]); mx = fmaxf(mx, st[mt][3]);
  }
  mx = fmaxf(mx, __shfl_xor(mx, 16));
  mx = fmaxf(mx, __shfl_xor(mx, 32));
  float sum = 0.f;
#pragma unroll
  for (int mt = 0; mt < 16; ++mt) {
#pragma unroll
    for (int r = 0; r < 4; ++r) {
      float e = __expf((st[mt][r] - mx) * SCALE_);
      st[mt][r] = e;
      sum += e;
    }
  }
  sum += __shfl_xor(sum, 16);
  sum += __shfl_xor(sum, 32);
  const float rinv = 1.f / sum;

  // All waves done reading K -> restage LDS with V (V^T page: 128 rows x 512B = 32 chunks).
  __syncthreads();
#pragma unroll
  for (int r = 0; r < 4; ++r) {
    const int u = tid + (r << 10);
    const int row = u >> 5, cc = u & 31;
    glds16(Vb + (size_t)(row * 32 + (cc ^ (row & 15))) * 16, (char*)Sm + u * 16);
  }
  __syncthreads();

  // ctx^T = V^T * P^T. A = V^T rows from LDS. B frag: lane supplies P^T[kt*32+quad*8+j][L].
  f32x4 ct[8];
#pragma unroll
  for (int mt = 0; mt < 8; ++mt) ct[mt] = f32x4{0.f, 0.f, 0.f, 0.f};
#pragma unroll
  for (int kt = 0; kt < 8; ++kt) {
    u16x8 pt;
#pragma unroll
    for (int j = 0; j < 8; ++j) {
      // element k2 = kt*32 + quad*8 + j lives in C-frag 2kt+(quad>>1),
      // source lane = (2*(quad&1)+(j>>2))*16 + L, reg = j&3
      const int src = ((quad & 1) * 2 + (j >> 2)) * 16 + L;
      float v0 = __shfl(st[2 * kt][j & 3], src);
      float v1 = __shfl(st[2 * kt + 1][j & 3], src);
      pt[j] = f2bf(quad < 2 ? v0 : v1);
    }
    bf16x8 pb = __builtin_bit_cast(bf16x8, pt);
    const int c = kt * 4 + quad;
#pragma unroll
    for (int mt = 0; mt < 8; ++mt) {
      bf16x8 a = *(const bf16x8*)((const char*)Sm + (mt * 16 + L) * 512 + ((c ^ L) << 4));
      ct[mt] = __builtin_amdgcn_mfma_f32_16x16x32_bf16(a, pb, ct[mt], 0, 0, 0);
    }
  }

  // Epilogue: ctx^T frag col = q (lane L), rows = d3. out[b][256h+q][128*h2+d3], bf16.
  const int b = x2 >> 4, h = x2 & 15;
  const int sg = h * 256 + q0 + L;
  u16* orow = ctx + ((size_t)b * 4096 + sg) * 2048 + h2 * 128;
#pragma unroll
  for (int mt = 0; mt < 8; ++mt) {
    U4 o = { f2bf(ct[mt][0] * rinv), f2bf(ct[mt][1] * rinv),
             f2bf(ct[mt][2] * rinv), f2bf(ct[mt][3] * rinv) };
    *(U4*)(orow + mt * 16 + quad * 4) = o;
  }
}

// ---------------- launch ----------------
extern "C" void kernel_launch(void* const* d_in, const int* in_sizes, int n_in,
                              void* d_out, int out_size, void* d_ws, size_t ws_size,
                              hipStream_t stream) {
  const float* X  = (const float*)d_in[0];
  const float* Wq = (const float*)d_in[1];
  const float* bq = (const float*)d_in[2];
  const float* Wk = (const float*)d_in[3];
  const float* bk = (const float*)d_in[4];
  const float* Wv = (const float*)d_in[5];
  const float* bv = (const float*)d_in[6];
  const float* Wo = (const float*)d_in[7];
  const float* bo = (const float*)d_in[8];

  static bool attr_set = false;
  if (!attr_set) {
    hipFuncSetAttribute((const void*)gemm_kernel,
                        hipFuncAttributeMaxDynamicSharedMemorySize, 131072);
    attr_set = true;
  }

  char* ws = (char*)d_ws;
  u16* Xb  = (u16*)(ws);                    // 64 MB
  u16* Wqb = (u16*)(ws + 67108864);         // 8 MB each
  u16* Wkb = (u16*)(ws + 75497472);
  u16* Wvb = (u16*)(ws + 83886080);
  u16* Wob = (u16*)(ws + 92274688);
  u16* Qp  = (u16*)(ws + 100663296);        // 64 MB paged
  u16* Kp  = (u16*)(ws + 167772160);        // 64 MB paged
  u16* Vt  = (u16*)(ws + 234881024);        // 64 MB transposed-paged
  u16* Cb  = (u16*)(ws + 301989888);        // 64 MB ctx bf16 (B,S,HID)

  cvt_kernel<<<32768, 256, 0, stream>>>(X,  Xb,  8388608);
  cvt_kernel<<<4096,  256, 0, stream>>>(Wq, Wqb, 1048576);
  cvt_kernel<<<4096,  256, 0, stream>>>(Wk, Wkb, 1048576);
  cvt_kernel<<<4096,  256, 0, stream>>>(Wv, Wvb, 1048576);
  cvt_kernel<<<4096,  256, 0, stream>>>(Wo, Wob, 1048576);

  gemm_kernel<<<512, 512, 131072, stream>>>(Xb, Wqb, bq, (void*)Qp, 0);
  gemm_kernel<<<512, 512, 131072, stream>>>(Xb, Wkb, bk, (void*)Kp, 0);
  gemm_kernel<<<512, 512, 131072, stream>>>(Xb, Wvb, bv, (void*)Vt, 1);

  attn_kernel<<<1024, 1024, 0, stream>>>(Qp, Kp, Vt, Cb);

  gemm_kernel<<<512, 512, 131072, stream>>>(Cb, Wob, bo, d_out, 2);
}

// Round 2
// 890.791 us; speedup vs baseline: 1.2795x; 1.0079x over previous
//
#include <hip/hip_runtime.h>

// PagedAttention fused pipeline for MI355X (gfx950).
// B=4 S=4096 HID=2048 H=16 P=256 D=128 N=16.
// Paged permutation (derived from flat strides of the unfold/reshape):
//   q/k/v:  heads[b,h,n*P+p,d] -> paged[x2=16b+h][h2=n][p2=2d+(p>>7)][d2=p&127]
//   output: ctx[x2][h2][p2][d3] -> out[b=x2>>4][s=256*(x2&15)+p2][c=128*h2+d3]
// GEMMs: 256x256 tile, BK=64, 8 waves (2x4), 8-phase schedule (T2+T3+T4+T5):
//   128KB double-buffered LDS, global_load_lds with inverse-swizzled source +
//   XOR-swizzled ds_read_b128. Staging confined to phases P3/P4/P7/P8 (4 loads
//   each) so every load has 4-5 phases of lead; counted vmcnt(8) at P4/P8.
// Block->tile map: XCD (bid&7) owns an 8-m-tile chunk of A; n varies slowly.

typedef unsigned short u16;
typedef unsigned int u32;
typedef __attribute__((ext_vector_type(8))) __bf16 bf16x8;
typedef __attribute__((ext_vector_type(4))) float f32x4;
typedef __attribute__((ext_vector_type(8))) u16 u16x8;

struct alignas(8) U4 { u16 x, y, z, w; };

#define SCALE_ 0.08838834764831845f

__device__ __forceinline__ u16 f2bf(float f) {
  union { float f; u32 u; } v; v.f = f;
  u32 r = v.u + 0x7fffu + ((v.u >> 16) & 1u);   // RNE
  return (u16)(r >> 16);
}

__device__ __forceinline__ void glds16(const void* g, void* l) {
  __builtin_amdgcn_global_load_lds(
      (const __attribute__((address_space(1))) u32*)g,
      (__attribute__((address_space(3))) u32*)l, 16, 0, 0);
}

// ---------------- fp32 -> bf16 conversion (vectorized x4) ----------------
__global__ void cvt_kernel(const float* __restrict__ src, u16* __restrict__ dst, int n4) {
  int i = blockIdx.x * 256 + threadIdx.x;
  if (i >= n4) return;
  float4 f = ((const float4*)src)[i];
  U4 o = { f2bf(f.x), f2bf(f.y), f2bf(f.z), f2bf(f.w) };
  ((U4*)dst)[i] = o;
}

// fused 4-weight cvt: dst buffers are contiguous 4 MiB-u16 panels
__global__ void cvtw_kernel(const float* __restrict__ s0, const float* __restrict__ s1,
                            const float* __restrict__ s2, const float* __restrict__ s3,
                            u16* __restrict__ d0, int n4) {
  const int w = blockIdx.y;
  const float* src = (w == 0) ? s0 : (w == 1) ? s1 : (w == 2) ? s2 : s3;
  u16* dst = d0 + (size_t)w * 4194304;
  int i = blockIdx.x * 256 + threadIdx.x;
  if (i >= n4) return;
  float4 f = ((const float4*)src)[i];
  U4 o = { f2bf(f.x), f2bf(f.y), f2bf(f.z), f2bf(f.w) };
  ((U4*)dst)[i] = o;
}

// ---------------- GEMM: C[m,n] = sum_k A[m,k]*W[n,k] + bias[n] ----------------
// 256x256 tile, BK=64, 512 threads (8 waves as 2Mx4N, each owns 128x64 output).
// mode 0: write bf16 paged layout (Q/K).  mode 1: write bf16 transposed-paged (V).
// mode 2: write fp32 row-major (final output).

#define MFMA_Q(AF, BF, MB, NB) do { \
  _Pragma("unroll") for (int mt_ = 0; mt_ < 4; ++mt_) \
  _Pragma("unroll") for (int nt_ = 0; nt_ < 2; ++nt_) \
  _Pragma("unroll") for (int kh_ = 0; kh_ < 2; ++kh_) \
    acc[(MB)+mt_][(NB)+nt_] = __builtin_amdgcn_mfma_f32_16x16x32_bf16( \
      AF[mt_][kh_], BF[nt_][kh_], acc[(MB)+mt_][(NB)+nt_], 0, 0, 0); \
} while (0)

#define LDA(F, MTB, BUF) do { \
  _Pragma("unroll") for (int mt_ = 0; mt_ < 4; ++mt_) { \
    F[mt_][0] = *(const bf16x8*)(aRd0 + (BUF)*65536 + ((MTB)+mt_)*2048); \
    F[mt_][1] = *(const bf16x8*)(aRd1 + (BUF)*65536 + ((MTB)+mt_)*2048); \
  } } while (0)

#define LDB(F, NTB, BUF) do { \
  _Pragma("unroll") for (int nt_ = 0; nt_ < 2; ++nt_) { \
    F[nt_][0] = *(const bf16x8*)(bRd0 + (BUF)*65536 + ((NTB)+nt_)*2048); \
    F[nt_][1] = *(const bf16x8*)(bRd1 + (BUF)*65536 + ((NTB)+nt_)*2048); \
  } } while (0)

// Stage half-tile H (128 rows) of the k-tile starting at element KK into BUF.
// LDS dest linear (base + tid*16); global source chunk inverse-swizzled.
#define STAGE_A(BUF, H, KK) do { \
  glds16(Asrc + (size_t)((H)*128) * 2048 + (KK), dstA + (BUF)*65536 + (H)*16384); \
  glds16(Asrc + (size_t)((H)*128 + 64) * 2048 + (KK), dstA + (BUF)*65536 + (H)*16384 + 8192); \
} while (0)

#define STAGE_B(BUF, H, KK) do { \
  glds16(Bsrc + (size_t)((H)*128) * 2048 + (KK), dstB + (BUF)*65536 + (H)*16384); \
  glds16(Bsrc + (size_t)((H)*128 + 64) * 2048 + (KK), dstB + (BUF)*65536 + (H)*16384 + 8192); \
} while (0)

#define PH_ENTER() do { \
  __builtin_amdgcn_s_barrier(); \
  asm volatile("s_waitcnt lgkmcnt(0)" ::: "memory"); \
  __builtin_amdgcn_sched_barrier(0); \
  __builtin_amdgcn_s_setprio(1); \
} while (0)

#define PH_EXIT() do { \
  __builtin_amdgcn_s_setprio(0); \
  __builtin_amdgcn_sched_barrier(0); \
  __builtin_amdgcn_s_barrier(); \
} while (0)

#define PH_EXIT_VM(N) do { \
  __builtin_amdgcn_s_setprio(0); \
  __builtin_amdgcn_sched_barrier(0); \
  asm volatile("s_waitcnt vmcnt(" #N ")" ::: "memory"); \
  __builtin_amdgcn_s_barrier(); \
} while (0)

#define LGKM_HINT() asm volatile("s_waitcnt lgkmcnt(8)" ::: "memory")

__global__ __launch_bounds__(512, 2) void gemm_kernel(
    const u16* __restrict__ A,
    const u16* __restrict__ W0, const u16* __restrict__ W1, const u16* __restrict__ W2,
    const float* __restrict__ b0, const float* __restrict__ b1, const float* __restrict__ b2,
    void* __restrict__ o0, void* __restrict__ o1, void* __restrict__ o2,
    int md0, int md1, int md2)
{
  extern __shared__ char Sm[];                 // 131072: buf{0,1} x {A:32KB, B:32KB}
  const int g = blockIdx.y;
  const u16* Bw     = (g == 0) ? W0 : (g == 1) ? W1 : W2;
  const float* bias = (g == 0) ? b0 : (g == 1) ? b1 : b2;
  void* outp        = (g == 0) ? o0 : (g == 1) ? o1 : o2;
  const int mode    = (g == 0) ? md0 : (g == 1) ? md1 : md2;

  const int tid  = threadIdx.x;
  const int lane = tid & 63;
  const int wid  = tid >> 6;
  const int L    = lane & 15;
  const int quad = lane >> 4;
  const int wm   = wid >> 2;                   // 0..1
  const int wn   = wid & 3;                    // 0..3
  // XCD-chunked map: XCD (bid&7) covers m-tiles [xcd*8, xcd*8+8) x all n.
  // m varies fastest within an XCD so concurrent blocks share B panels (L2)
  // and the per-XCD A chunk (8MB) stays L3-resident.
  const int bid = blockIdx.x;
  const int xcd = bid & 7;
  const int idx = bid >> 3;                    // 0..63
  const int m0 = (xcd * 8 + (idx & 7)) << 8;
  const int n0 = (idx >> 3) << 8;

  // staging: thread covers LDS chunk u=tid (and u=tid+512) of each half-tile.
  const int srow = tid >> 3;                   // 0..63 (row within 64-row stripe)
  const int scs  = (tid & 7) ^ (srow & 7);     // inverse-swizzled source chunk
  const u16* Asrc = A  + (size_t)(m0 + srow) * 2048 + scs * 8;
  const u16* Bsrc = Bw + (size_t)(n0 + srow) * 2048 + scs * 8;
  char* dstA = Sm + tid * 16;
  char* dstB = Sm + 32768 + tid * 16;

  // fragment read bases: row = (wm*128|wn*64) + <t>*16 + L, chunk (kh*4+quad)^(L&7)
  const int xA = ((quad ^ (L & 7)) << 4);
  const char* aRd0 = Sm + (wm * 128 + L) * 128 + xA;
  const char* aRd1 = Sm + (wm * 128 + L) * 128 + (xA ^ 64);
  const char* bRd0 = Sm + 32768 + (wn * 64 + L) * 128 + xA;
  const char* bRd1 = Sm + 32768 + (wn * 64 + L) * 128 + (xA ^ 64);

  f32x4 acc[8][4];
#pragma unroll
  for (int i = 0; i < 8; ++i)
#pragma unroll
    for (int j = 0; j < 4; ++j)
      acc[i][j] = f32x4{0.f, 0.f, 0.f, 0.f};

  bf16x8 aLo[4][2], aHi[4][2], bLo[2][2], bHi[2][2];

  // Prologue: buf0 <- tile0, buf1 <- tile1 (16 loads); drain tile0's 8.
  STAGE_A(0, 0, 0);
  STAGE_A(0, 1, 0);
  STAGE_B(0, 0, 0);
  STAGE_B(0, 1, 0);
  STAGE_A(1, 0, 64);
  STAGE_A(1, 1, 64);
  STAGE_B(1, 0, 64);
  STAGE_B(1, 1, 64);
  asm volatile("s_waitcnt vmcnt(8)" ::: "memory");
  __builtin_amdgcn_s_barrier();

  // 16 iterations x 2 k-tiles (buf0: tile 2it, buf1: tile 2it+1).
  // Stages only in P3/P4 (buf0 <- tile 2it+2) and P7/P8 (buf1 <- tile 2it+3);
  // vmcnt(8) gates at P4 (buf1 ready) and P8 (buf0 ready). Leads: A 5ph, B 4ph.
#pragma unroll 1
  for (int it = 0; it < 16; ++it) {
    const int kb = it * 128;
    // ---- P1 ----
    LDA(aLo, 0, 0); LDB(bLo, 0, 0);
    LGKM_HINT();
    PH_ENTER();
    MFMA_Q(aLo, bLo, 0, 0);
    PH_EXIT();
    // ---- P2 ----
    LDA(aHi, 4, 0); LDB(bHi, 2, 0);
    LGKM_HINT();
    PH_ENTER();
    MFMA_Q(aLo, bHi, 0, 2);
    PH_EXIT();
    // ---- P3 ---- (buf0 consumed; restage A half-tiles)
    if (it < 15) { STAGE_A(0, 0, kb + 128); STAGE_A(0, 1, kb + 128); }
    PH_ENTER();
    MFMA_Q(aHi, bLo, 4, 0);
    PH_EXIT();
    // ---- P4 ---- (restage buf0 B; gate: buf1 fully landed)
    if (it < 15) { STAGE_B(0, 0, kb + 128); STAGE_B(0, 1, kb + 128); }
    PH_ENTER();
    MFMA_Q(aHi, bHi, 4, 2);
    if (it < 15) { PH_EXIT_VM(8); } else { PH_EXIT_VM(0); }
    // ---- P5 ----
    LDA(aLo, 0, 1); LDB(bLo, 0, 1);
    LGKM_HINT();
    PH_ENTER();
    MFMA_Q(aLo, bLo, 0, 0);
    PH_EXIT();
    // ---- P6 ----
    LDA(aHi, 4, 1); LDB(bHi, 2, 1);
    LGKM_HINT();
    PH_ENTER();
    MFMA_Q(aLo, bHi, 0, 2);
    PH_EXIT();
    // ---- P7 ---- (buf1 consumed; restage A half-tiles)
    if (it < 15) { STAGE_A(1, 0, kb + 192); STAGE_A(1, 1, kb + 192); }
    PH_ENTER();
    MFMA_Q(aHi, bLo, 4, 0);
    PH_EXIT();
    // ---- P8 ---- (restage buf1 B; gate: buf0 fully landed)
    if (it < 15) { STAGE_B(1, 0, kb + 192); STAGE_B(1, 1, kb + 192); }
    PH_ENTER();
    MFMA_Q(aHi, bHi, 4, 2);
    if (it < 15) { PH_EXIT_VM(8); } else { PH_EXIT(); }
  }

  // Epilogue. C frag: col = lane&15 (n), rows = quad*4 + reg (m).
#pragma unroll
  for (int nt = 0; nt < 4; ++nt) {
    const int c = n0 + wn * 64 + nt * 16 + L;
    const float bv = bias[c];
    const int h = c >> 7, d = c & 127;
#pragma unroll
    for (int mt = 0; mt < 8; ++mt) {
      const int sg = m0 + wm * 128 + mt * 16 + (quad << 2);   // global row in (B*S)
      const int b   = sg >> 12;
      const int s   = sg & 4095;
      const int npg = (s >> 8) & 15;
      const int half = (s >> 7) & 1;
      const int plo  = s & 127;                 // consecutive for the 4 regs
      const f32x4 v = acc[mt][nt];
      const size_t bb = ((size_t)((b * 16 + h) * 16 + npg)) << 15;  // *32768
      if (mode == 0) {
        U4 o = { f2bf(v[0] + bv), f2bf(v[1] + bv), f2bf(v[2] + bv), f2bf(v[3] + bv) };
        *(U4*)((u16*)outp + bb + (size_t)(2 * d + half) * 128 + plo) = o;
      } else if (mode == 1) {
        u16* o16 = (u16*)outp + bb + 2 * d + half;
        o16[(size_t)(plo + 0) * 256] = f2bf(v[0] + bv);
        o16[(size_t)(plo + 1) * 256] = f2bf(v[1] + bv);
        o16[(size_t)(plo + 2) * 256] = f2bf(v[2] + bv);
        o16[(size_t)(plo + 3) * 256] = f2bf(v[3] + bv);
      } else {
        float* of = (float*)outp + (size_t)sg * 2048 + c;
        of[0]    = v[0] + bv;
        of[2048] = v[1] + bv;
        of[4096] = v[2] + bv;
        of[6144] = v[3] + bv;
      }
    }
  }
}

// ---------------- Attention: one block (1024 thr, 16 waves) per page ----------------
// Stage K (64KB) into LDS with XOR-swizzled 16B-chunk placement (conflict-free
// fragment reads), compute S^T = K*Q^T, softmax in-register, then reuse the LDS
// for V and compute ctx^T = V^T * P^T (P^T B-frags built by shuffles).
__global__ __launch_bounds__(1024, 4) void attn_kernel(
    const u16* __restrict__ Qp, const u16* __restrict__ Kp,
    const u16* __restrict__ Vt, u16* __restrict__ ctx)
{
  __shared__ u16 Sm[32768];                    // 64 KB, holds K then V
  const int tid  = threadIdx.x;
  const int wid  = tid >> 6;
  const int lane = tid & 63;
  const int L    = lane & 15;
  const int quad = lane >> 4;
  const int pg   = blockIdx.x;                 // page = x2*16 + h2
  const int x2 = pg >> 4, h2 = pg & 15;
  const int q0 = wid * 16;                     // 16 queries per wave

  const char* Qb = (const char*)(Qp + (size_t)pg * 32768);
  const char* Kb = (const char*)(Kp + (size_t)pg * 32768);
  const char* Vb = (const char*)(Vt + (size_t)pg * 32768);

  // Stage K: LDS slot u (16B chunks): row=u>>4, cc=u&15; fetch global chunk
  // row*16 + (cc ^ (row&15)) so that K[row][c] lives at slot row*16 + (c^(row&15)).
#pragma unroll
  for (int r = 0; r < 4; ++r) {
    const int u = tid + (r << 10);
    const int row = u >> 4, cc = u & 15;
    glds16(Kb + (size_t)(row * 16 + (cc ^ (row & 15))) * 16, (char*)Sm + u * 16);
  }

  // Q B-frags: B[k=d][n=q], lane holds Q[q0+L][kt*32+quad*8+j] (row-contiguous)
  bf16x8 qf[4];
#pragma unroll
  for (int kt = 0; kt < 4; ++kt)
    qf[kt] = *(const bf16x8*)(Qb + (q0 + L) * 256 + kt * 64 + quad * 16);

  __syncthreads();

  // S^T accumulate: rows k2 (16 tiles), cols q (16). A = K rows from LDS.
  // Read K[row=mt*16+L][chunk c=kt*4+quad] at swizzled offset (c^L)*16.
  f32x4 st[16];
#pragma unroll
  for (int mt = 0; mt < 16; ++mt) st[mt] = f32x4{0.f, 0.f, 0.f, 0.f};
#pragma unroll
  for (int kt = 0; kt < 4; ++kt) {
    const int c = kt * 4 + quad;
#pragma unroll
    for (int mt = 0; mt < 16; ++mt) {
      bf16x8 a = *(const bf16x8*)((const char*)Sm + (mt * 16 + L) * 256 + ((c ^ L) << 4));
      st[mt] = __builtin_amdgcn_mfma_f32_16x16x32_bf16(a, qf[kt], st[mt], 0, 0, 0);
    }
  }

  // softmax over k2 for this lane's q (=L): 64 in-lane values + lanes {L,L+16,L+32,L+48}
  float mx = -3.0e38f;
#pragma unroll
  for (int mt = 0; mt < 16; ++mt) {
    mx = fmaxf(mx, st[mt][0]); mx = fmaxf(mx, st[mt][1]);
    mx = fmaxf(mx, st[mt][2]); mx = fmaxf(mx, st[mt][3]);
  }
  mx = fmaxf(mx, __shfl_xor(mx, 16));
  mx = fmaxf(mx, __shfl_xor(mx, 32));
  float sum = 0.f;
#pragma unroll
  for (int mt = 0; mt < 16; ++mt) {
#pragma unroll
    for (int r = 0; r < 4; ++r) {
      float e = __expf((st[mt][r] - mx) * SCALE_);
      st[mt][r] = e;
      sum += e;
    }
  }
  sum += __shfl_xor(sum, 16);
  sum += __shfl_xor(sum, 32);
  const float rinv = 1.f / sum;

  // All waves done reading K -> restage LDS with V (V^T page: 128 rows x 512B = 32 chunks).
  __syncthreads();
#pragma unroll
  for (int r = 0; r < 4; ++r) {
    const int u = tid + (r << 10);
    const int row = u >> 5, cc = u & 31;
    glds16(Vb + (size_t)(row * 32 + (cc ^ (row & 15))) * 16, (char*)Sm + u * 16);
  }
  __syncthreads();

  // ctx^T = V^T * P^T. A = V^T rows from LDS. B frag: lane supplies P^T[kt*32+quad*8+j][L].
  f32x4 ct[8];
#pragma unroll
  for (int mt = 0; mt < 8; ++mt) ct[mt] = f32x4{0.f, 0.f, 0.f, 0.f};
#pragma unroll
  for (int kt = 0; kt < 8; ++kt) {
    u16x8 pt;
#pragma unroll
    for (int j = 0; j < 8; ++j) {
      // element k2 = kt*32 + quad*8 + j lives in C-frag 2kt+(quad>>1),
      // source lane = (2*(quad&1)+(j>>2))*16 + L, reg = j&3
      const int src = ((quad & 1) * 2 + (j >> 2)) * 16 + L;
      float v0 = __shfl(st[2 * kt][j & 3], src);
      float v1 = __shfl(st[2 * kt + 1][j & 3], src);
      pt[j] = f2bf(quad < 2 ? v0 : v1);
    }
    bf16x8 pb = __builtin_bit_cast(bf16x8, pt);
    const int c = kt * 4 + quad;
#pragma unroll
    for (int mt = 0; mt < 8; ++mt) {
      bf16x8 a = *(const bf16x8*)((const char*)Sm + (mt * 16 + L) * 512 + ((c ^ L) << 4));
      ct[mt] = __builtin_amdgcn_mfma_f32_16x16x32_bf16(a, pb, ct[mt], 0, 0, 0);
    }
  }

  // Epilogue: ctx^T frag col = q (lane L), rows = d3. out[b][256h+q][128*h2+d3], bf16.
  const int b = x2 >> 4, h = x2 & 15;
  const int sg = h * 256 + q0 + L;
  u16* orow = ctx + ((size_t)b * 4096 + sg) * 2048 + h2 * 128;
#pragma unroll
  for (int mt = 0; mt < 8; ++mt) {
    U4 o = { f2bf(ct[mt][0] * rinv), f2bf(ct[mt][1] * rinv),
             f2bf(ct[mt][2] * rinv), f2bf(ct[mt][3] * rinv) };
    *(U4*)(orow + mt * 16 + quad * 4) = o;
  }
}

// ---------------- launch ----------------
extern "C" void kernel_launch(void* const* d_in, const int* in_sizes, int n_in,
                              void* d_out, int out_size, void* d_ws, size_t ws_size,
                              hipStream_t stream) {
  const float* X  = (const float*)d_in[0];
  const float* Wq = (const float*)d_in[1];
  const float* bq = (const float*)d_in[2];
  const float* Wk = (const float*)d_in[3];
  const float* bk = (const float*)d_in[4];
  const float* Wv = (const float*)d_in[5];
  const float* bv = (const float*)d_in[6];
  const float* Wo = (const float*)d_in[7];
  const float* bo = (const float*)d_in[8];

  static bool attr_set = false;
  if (!attr_set) {
    hipFuncSetAttribute((const void*)gemm_kernel,
                        hipFuncAttributeMaxDynamicSharedMemorySize, 131072);
    attr_set = true;
  }

  char* ws = (char*)d_ws;
  u16* Xb  = (u16*)(ws);                    // 64 MB
  u16* Wqb = (u16*)(ws + 67108864);         // 8 MB each (Wq,Wk,Wv,Wo contiguous)
  u16* Qp  = (u16*)(ws + 100663296);        // 64 MB paged
  u16* Kp  = (u16*)(ws + 167772160);        // 64 MB paged
  u16* Vt  = (u16*)(ws + 234881024);        // 64 MB transposed-paged
  u16* Cb  = (u16*)(ws + 301989888);        // 64 MB ctx bf16 (B,S,HID)
  u16* Wkb = Wqb + 4194304;
  u16* Wvb = Wqb + 8388608;
  u16* Wob = Wqb + 12582912;

  cvt_kernel<<<32768, 256, 0, stream>>>(X, Xb, 8388608);
  cvtw_kernel<<<dim3(4096, 4), 256, 0, stream>>>(Wq, Wk, Wv, Wo, Wqb, 1048576);

  gemm_kernel<<<dim3(512, 3), 512, 131072, stream>>>(
      Xb, Wqb, Wkb, Wvb, bq, bk, bv, (void*)Qp, (void*)Kp, (void*)Vt, 0, 0, 1);

  attn_kernel<<<1024, 1024, 0, stream>>>(Qp, Kp, Vt, Cb);

  gemm_kernel<<<dim3(512, 1), 512, 131072, stream>>>(
      Cb, Wob, Wob, Wob, bo, bo, bo, d_out, d_out, d_out, 2, 2, 2);
}

// Round 3
// 874.921 us; speedup vs baseline: 1.3027x; 1.0181x over previous
//
#include <hip/hip_runtime.h>

// PagedAttention fused pipeline for MI355X (gfx950).
// B=4 S=4096 HID=2048 H=16 P=256 D=128 N=16.
// Paged permutation (derived from flat strides of the unfold/reshape):
//   q/k/v:  heads[b,h,n*P+p,d] -> paged[x2=16b+h][h2=n][p2=2d+(p>>7)][d2=p&127]
//   output: ctx[x2][h2][p2][d3] -> out[b=x2>>4][s=256*(x2&15)+p2][c=128*h2+d3]
// GEMMs: 256x256 tile, BK=64, 8 waves (2x4), 8-phase schedule (T2+T3+T4+T5).
// Frag reads spread {8,8,4,4}/phase via carried-bLo pipeline (next tile's bLo
// loaded in phase 4 into the vacated set) so per-phase LDS drain ~= MFMA time.
// Stages at P4/P5 (buf0) and P8 (buf1, 8 glds); vmcnt(0) gates at P3/P7 exits.
// Block->tile map: XCD (bid&7) owns an 8-m-tile chunk of A; n varies slowly.

typedef unsigned short u16;
typedef unsigned int u32;
typedef __attribute__((ext_vector_type(8))) __bf16 bf16x8;
typedef __attribute__((ext_vector_type(4))) float f32x4;
typedef __attribute__((ext_vector_type(8))) u16 u16x8;

struct alignas(8) U4 { u16 x, y, z, w; };

#define SCALE_ 0.08838834764831845f

__device__ __forceinline__ u16 f2bf(float f) {
  union { float f; u32 u; } v; v.f = f;
  u32 r = v.u + 0x7fffu + ((v.u >> 16) & 1u);   // RNE
  return (u16)(r >> 16);
}

__device__ __forceinline__ void glds16(const void* g, void* l) {
  __builtin_amdgcn_global_load_lds(
      (const __attribute__((address_space(1))) u32*)g,
      (__attribute__((address_space(3))) u32*)l, 16, 0, 0);
}

// ---------------- fp32 -> bf16 conversion (vectorized x4) ----------------
__global__ void cvt_kernel(const float* __restrict__ src, u16* __restrict__ dst, int n4) {
  int i = blockIdx.x * 256 + threadIdx.x;
  if (i >= n4) return;
  float4 f = ((const float4*)src)[i];
  U4 o = { f2bf(f.x), f2bf(f.y), f2bf(f.z), f2bf(f.w) };
  ((U4*)dst)[i] = o;
}

// fused 4-weight cvt: dst buffers are contiguous 4 MiB-u16 panels
__global__ void cvtw_kernel(const float* __restrict__ s0, const float* __restrict__ s1,
                            const float* __restrict__ s2, const float* __restrict__ s3,
                            u16* __restrict__ d0, int n4) {
  const int w = blockIdx.y;
  const float* src = (w == 0) ? s0 : (w == 1) ? s1 : (w == 2) ? s2 : s3;
  u16* dst = d0 + (size_t)w * 4194304;
  int i = blockIdx.x * 256 + threadIdx.x;
  if (i >= n4) return;
  float4 f = ((const float4*)src)[i];
  U4 o = { f2bf(f.x), f2bf(f.y), f2bf(f.z), f2bf(f.w) };
  ((U4*)dst)[i] = o;
}

// ---------------- GEMM: C[m,n] = sum_k A[m,k]*W[n,k] + bias[n] ----------------
// mode 0: write bf16 paged layout (Q/K).  mode 1: write bf16 transposed-paged (V).
// mode 2: write fp32 row-major (final output).

#define MFMA_Q(AF, BF, MB, NB) do { \
  _Pragma("unroll") for (int mt_ = 0; mt_ < 4; ++mt_) \
  _Pragma("unroll") for (int nt_ = 0; nt_ < 2; ++nt_) \
  _Pragma("unroll") for (int kh_ = 0; kh_ < 2; ++kh_) \
    acc[(MB)+mt_][(NB)+nt_] = __builtin_amdgcn_mfma_f32_16x16x32_bf16( \
      AF[mt_][kh_], BF[nt_][kh_], acc[(MB)+mt_][(NB)+nt_], 0, 0, 0); \
} while (0)

#define LDA(F, MTB, BUF) do { \
  _Pragma("unroll") for (int mt_ = 0; mt_ < 4; ++mt_) { \
    F[mt_][0] = *(const bf16x8*)(aRd0 + (BUF)*65536 + ((MTB)+mt_)*2048); \
    F[mt_][1] = *(const bf16x8*)(aRd1 + (BUF)*65536 + ((MTB)+mt_)*2048); \
  } } while (0)

#define LDB(F, NTB, BUF) do { \
  _Pragma("unroll") for (int nt_ = 0; nt_ < 2; ++nt_) { \
    F[nt_][0] = *(const bf16x8*)(bRd0 + (BUF)*65536 + ((NTB)+nt_)*2048); \
    F[nt_][1] = *(const bf16x8*)(bRd1 + (BUF)*65536 + ((NTB)+nt_)*2048); \
  } } while (0)

// Stage half-tile H (128 rows) of the k-tile starting at element KK into BUF.
// LDS dest linear (base + tid*16); global source chunk inverse-swizzled.
#define STAGE_A(BUF, H, KK) do { \
  glds16(Asrc + (size_t)((H)*128) * 2048 + (KK), dstA + (BUF)*65536 + (H)*16384); \
  glds16(Asrc + (size_t)((H)*128 + 64) * 2048 + (KK), dstA + (BUF)*65536 + (H)*16384 + 8192); \
} while (0)

#define STAGE_B(BUF, H, KK) do { \
  glds16(Bsrc + (size_t)((H)*128) * 2048 + (KK), dstB + (BUF)*65536 + (H)*16384); \
  glds16(Bsrc + (size_t)((H)*128 + 64) * 2048 + (KK), dstB + (BUF)*65536 + (H)*16384 + 8192); \
} while (0)

#define PH_ENTER() do { \
  __builtin_amdgcn_s_barrier(); \
  asm volatile("s_waitcnt lgkmcnt(0)" ::: "memory"); \
  __builtin_amdgcn_sched_barrier(0); \
  __builtin_amdgcn_s_setprio(1); \
} while (0)

#define PH_EXIT() do { \
  __builtin_amdgcn_s_setprio(0); \
  __builtin_amdgcn_sched_barrier(0); \
  __builtin_amdgcn_s_barrier(); \
} while (0)

#define PH_EXIT_VM(N) do { \
  __builtin_amdgcn_s_setprio(0); \
  __builtin_amdgcn_sched_barrier(0); \
  asm volatile("s_waitcnt vmcnt(" #N ")" ::: "memory"); \
  __builtin_amdgcn_s_barrier(); \
} while (0)

__global__ __launch_bounds__(512, 2) void gemm_kernel(
    const u16* __restrict__ A,
    const u16* __restrict__ W0, const u16* __restrict__ W1, const u16* __restrict__ W2,
    const float* __restrict__ b0, const float* __restrict__ b1, const float* __restrict__ b2,
    void* __restrict__ o0, void* __restrict__ o1, void* __restrict__ o2,
    int md0, int md1, int md2)
{
  extern __shared__ char Sm[];                 // 131072: buf{0,1} x {A:32KB, B:32KB}
  const int g = blockIdx.y;
  const u16* Bw     = (g == 0) ? W0 : (g == 1) ? W1 : W2;
  const float* bias = (g == 0) ? b0 : (g == 1) ? b1 : b2;
  void* outp        = (g == 0) ? o0 : (g == 1) ? o1 : o2;
  const int mode    = (g == 0) ? md0 : (g == 1) ? md1 : md2;

  const int tid  = threadIdx.x;
  const int lane = tid & 63;
  const int wid  = tid >> 6;
  const int L    = lane & 15;
  const int quad = lane >> 4;
  const int wm   = wid >> 2;                   // 0..1
  const int wn   = wid & 3;                    // 0..3
  // XCD-chunked map: XCD (bid&7) covers m-tiles [xcd*8, xcd*8+8) x all n.
  const int bid = blockIdx.x;
  const int xcd = bid & 7;
  const int idx = bid >> 3;                    // 0..63
  const int m0 = (xcd * 8 + (idx & 7)) << 8;
  const int n0 = (idx >> 3) << 8;

  // staging: thread covers LDS chunk u=tid (and u=tid+512) of each half-tile.
  const int srow = tid >> 3;                   // 0..63 (row within 64-row stripe)
  const int scs  = (tid & 7) ^ (srow & 7);     // inverse-swizzled source chunk
  const u16* Asrc = A  + (size_t)(m0 + srow) * 2048 + scs * 8;
  const u16* Bsrc = Bw + (size_t)(n0 + srow) * 2048 + scs * 8;
  char* dstA = Sm + tid * 16;
  char* dstB = Sm + 32768 + tid * 16;

  // fragment read bases: row = (wm*128|wn*64) + <t>*16 + L, chunk (kh*4+quad)^(L&7)
  const int xA = ((quad ^ (L & 7)) << 4);
  const char* aRd0 = Sm + (wm * 128 + L) * 128 + xA;
  const char* aRd1 = Sm + (wm * 128 + L) * 128 + (xA ^ 64);
  const char* bRd0 = Sm + 32768 + (wn * 64 + L) * 128 + xA;
  const char* bRd1 = Sm + 32768 + (wn * 64 + L) * 128 + (xA ^ 64);

  f32x4 acc[8][4];
#pragma unroll
  for (int i = 0; i < 8; ++i)
#pragma unroll
    for (int j = 0; j < 4; ++j)
      acc[i][j] = f32x4{0.f, 0.f, 0.f, 0.f};

  bf16x8 aL[4][2], aH[4][2], b0f[2][2], b1f[2][2];

  // Prologue: stage buf0 <- tile0, buf1 <- tile1 (16 glds), drain, preload
  // b0f = tile0's bLo (normally carried in from a previous P4).
  STAGE_A(0, 0, 0);  STAGE_A(0, 1, 0);
  STAGE_B(0, 0, 0);  STAGE_B(0, 1, 0);
  STAGE_A(1, 0, 64); STAGE_A(1, 1, 64);
  STAGE_B(1, 0, 64); STAGE_B(1, 1, 64);
  asm volatile("s_waitcnt vmcnt(0)" ::: "memory");
  __builtin_amdgcn_s_barrier();
  LDB(b0f, 0, 0);

  // 16 iterations x 2 k-tiles (buf0: tile 2it, buf1: tile 2it+1).
  // Per tile, quadrant order (aL,b0)->(aH,b0)->(aH,b1)->(aL,b1); phase 4 of a
  // tile loads the NEXT tile's bLo into the vacated b0f set (cross-buf carry).
  // Reads/phase: 8,8,4,4. Stages: P4/P5 -> buf0 (tile+2), P8 -> buf1 (tile+3).
  // Gates: vmcnt(0) at P3-exit (buf1 staged) and P7-exit (buf0 staged).
#pragma unroll 1
  for (int it = 0; it < 16; ++it) {
    const int kb = it * 128;
    // ---- P1 ---- read aL<-buf0 (8)
    LDA(aL, 0, 0);
    PH_ENTER();
    MFMA_Q(aL, b0f, 0, 0);
    PH_EXIT();
    // ---- P2 ---- read aH<-buf0 (8)
    LDA(aH, 4, 0);
    PH_ENTER();
    MFMA_Q(aH, b0f, 4, 0);
    PH_EXIT();
    // ---- P3 ---- read b1<-buf0 (4); gate: buf1 fully landed
    LDB(b1f, 2, 0);
    PH_ENTER();
    MFMA_Q(aH, b1f, 4, 2);
    PH_EXIT_VM(0);
    // ---- P4 ---- read b0<-buf1 (tile1 bLo, 4); stage buf0.A <- tile+2
    LDB(b0f, 0, 1);
    if (it < 15) { STAGE_A(0, 0, kb + 128); STAGE_A(0, 1, kb + 128); }
    PH_ENTER();
    MFMA_Q(aL, b1f, 0, 2);
    PH_EXIT();
    // ---- P5 ---- read aL<-buf1 (8); stage buf0.B <- tile+2
    LDA(aL, 0, 1);
    if (it < 15) { STAGE_B(0, 0, kb + 128); STAGE_B(0, 1, kb + 128); }
    PH_ENTER();
    MFMA_Q(aL, b0f, 0, 0);
    PH_EXIT();
    // ---- P6 ---- read aH<-buf1 (8)
    LDA(aH, 4, 1);
    PH_ENTER();
    MFMA_Q(aH, b0f, 4, 0);
    PH_EXIT();
    // ---- P7 ---- read b1<-buf1 (4); gate: buf0' fully landed
    LDB(b1f, 2, 1);
    PH_ENTER();
    MFMA_Q(aH, b1f, 4, 2);
    PH_EXIT_VM(0);
    // ---- P8 ---- read b0<-buf0' (tile+2 bLo, 4); stage buf1 <- tile+3 (8 glds)
    if (it < 15) {
      LDB(b0f, 0, 0);
      STAGE_A(1, 0, kb + 192); STAGE_A(1, 1, kb + 192);
      STAGE_B(1, 0, kb + 192); STAGE_B(1, 1, kb + 192);
    }
    PH_ENTER();
    MFMA_Q(aL, b1f, 0, 2);
    PH_EXIT();
  }

  // Epilogue. C frag: col = lane&15 (n), rows = quad*4 + reg (m).
#pragma unroll
  for (int nt = 0; nt < 4; ++nt) {
    const int c = n0 + wn * 64 + nt * 16 + L;
    const float bv = bias[c];
    const int h = c >> 7, d = c & 127;
#pragma unroll
    for (int mt = 0; mt < 8; ++mt) {
      const int sg = m0 + wm * 128 + mt * 16 + (quad << 2);   // global row in (B*S)
      const int b   = sg >> 12;
      const int s   = sg & 4095;
      const int npg = (s >> 8) & 15;
      const int half = (s >> 7) & 1;
      const int plo  = s & 127;                 // consecutive for the 4 regs
      const f32x4 v = acc[mt][nt];
      const size_t bb = ((size_t)((b * 16 + h) * 16 + npg)) << 15;  // *32768
      if (mode == 0) {
        U4 o = { f2bf(v[0] + bv), f2bf(v[1] + bv), f2bf(v[2] + bv), f2bf(v[3] + bv) };
        *(U4*)((u16*)outp + bb + (size_t)(2 * d + half) * 128 + plo) = o;
      } else if (mode == 1) {
        u16* o16 = (u16*)outp + bb + 2 * d + half;
        o16[(size_t)(plo + 0) * 256] = f2bf(v[0] + bv);
        o16[(size_t)(plo + 1) * 256] = f2bf(v[1] + bv);
        o16[(size_t)(plo + 2) * 256] = f2bf(v[2] + bv);
        o16[(size_t)(plo + 3) * 256] = f2bf(v[3] + bv);
      } else {
        float* of = (float*)outp + (size_t)sg * 2048 + c;
        of[0]    = v[0] + bv;
        of[2048] = v[1] + bv;
        of[4096] = v[2] + bv;
        of[6144] = v[3] + bv;
      }
    }
  }
}

// ---------------- Attention: one block (1024 thr, 16 waves) per page ----------------
__global__ __launch_bounds__(1024, 4) void attn_kernel(
    const u16* __restrict__ Qp, const u16* __restrict__ Kp,
    const u16* __restrict__ Vt, u16* __restrict__ ctx)
{
  __shared__ u16 Sm[32768];                    // 64 KB, holds K then V
  const int tid  = threadIdx.x;
  const int wid  = tid >> 6;
  const int lane = tid & 63;
  const int L    = lane & 15;
  const int quad = lane >> 4;
  const int pg   = blockIdx.x;                 // page = x2*16 + h2
  const int x2 = pg >> 4, h2 = pg & 15;
  const int q0 = wid * 16;                     // 16 queries per wave

  const char* Qb = (const char*)(Qp + (size_t)pg * 32768);
  const char* Kb = (const char*)(Kp + (size_t)pg * 32768);
  const char* Vb = (const char*)(Vt + (size_t)pg * 32768);

#pragma unroll
  for (int r = 0; r < 4; ++r) {
    const int u = tid + (r << 10);
    const int row = u >> 4, cc = u & 15;
    glds16(Kb + (size_t)(row * 16 + (cc ^ (row & 15))) * 16, (char*)Sm + u * 16);
  }

  bf16x8 qf[4];
#pragma unroll
  for (int kt = 0; kt < 4; ++kt)
    qf[kt] = *(const bf16x8*)(Qb + (q0 + L) * 256 + kt * 64 + quad * 16);

  __syncthreads();

  f32x4 st[16];
#pragma unroll
  for (int mt = 0; mt < 16; ++mt) st[mt] = f32x4{0.f, 0.f, 0.f, 0.f};
#pragma unroll
  for (int kt = 0; kt < 4; ++kt) {
    const int c = kt * 4 + quad;
#pragma unroll
    for (int mt = 0; mt < 16; ++mt) {
      bf16x8 a = *(const bf16x8*)((const char*)Sm + (mt * 16 + L) * 256 + ((c ^ L) << 4));
      st[mt] = __builtin_amdgcn_mfma_f32_16x16x32_bf16(a, qf[kt], st[mt], 0, 0, 0);
    }
  }

  float mx = -3.0e38f;
#pragma unroll
  for (int mt = 0; mt < 16; ++mt) {
    mx = fmaxf(mx, st[mt][0]); mx = fmaxf(mx, st[mt][1]);
    mx = fmaxf(mx, st[mt][2]); mx = fmaxf(mx, st[mt][3]);
  }
  mx = fmaxf(mx, __shfl_xor(mx, 16));
  mx = fmaxf(mx, __shfl_xor(mx, 32));
  float sum = 0.f;
#pragma unroll
  for (int mt = 0; mt < 16; ++mt) {
#pragma unroll
    for (int r = 0; r < 4; ++r) {
      float e = __expf((st[mt][r] - mx) * SCALE_);
      st[mt][r] = e;
      sum += e;
    }
  }
  sum += __shfl_xor(sum, 16);
  sum += __shfl_xor(sum, 32);
  const float rinv = 1.f / sum;

  __syncthreads();
#pragma unroll
  for (int r = 0; r < 4; ++r) {
    const int u = tid + (r << 10);
    const int row = u >> 5, cc = u & 31;
    glds16(Vb + (size_t)(row * 32 + (cc ^ (row & 15))) * 16, (char*)Sm + u * 16);
  }
  __syncthreads();

  f32x4 ct[8];
#pragma unroll
  for (int mt = 0; mt < 8; ++mt) ct[mt] = f32x4{0.f, 0.f, 0.f, 0.f};
#pragma unroll
  for (int kt = 0; kt < 8; ++kt) {
    u16x8 pt;
#pragma unroll
    for (int j = 0; j < 8; ++j) {
      const int src = ((quad & 1) * 2 + (j >> 2)) * 16 + L;
      float v0 = __shfl(st[2 * kt][j & 3], src);
      float v1 = __shfl(st[2 * kt + 1][j & 3], src);
      pt[j] = f2bf(quad < 2 ? v0 : v1);
    }
    bf16x8 pb = __builtin_bit_cast(bf16x8, pt);
    const int c = kt * 4 + quad;
#pragma unroll
    for (int mt = 0; mt < 8; ++mt) {
      bf16x8 a = *(const bf16x8*)((const char*)Sm + (mt * 16 + L) * 512 + ((c ^ L) << 4));
      ct[mt] = __builtin_amdgcn_mfma_f32_16x16x32_bf16(a, pb, ct[mt], 0, 0, 0);
    }
  }

  const int b = x2 >> 4, h = x2 & 15;
  const int sg = h * 256 + q0 + L;
  u16* orow = ctx + ((size_t)b * 4096 + sg) * 2048 + h2 * 128;
#pragma unroll
  for (int mt = 0; mt < 8; ++mt) {
    U4 o = { f2bf(ct[mt][0] * rinv), f2bf(ct[mt][1] * rinv),
             f2bf(ct[mt][2] * rinv), f2bf(ct[mt][3] * rinv) };
    *(U4*)(orow + mt * 16 + quad * 4) = o;
  }
}

// ---------------- launch ----------------
extern "C" void kernel_launch(void* const* d_in, const int* in_sizes, int n_in,
                              void* d_out, int out_size, void* d_ws, size_t ws_size,
                              hipStream_t stream) {
  const float* X  = (const float*)d_in[0];
  const float* Wq = (const float*)d_in[1];
  const float* bq = (const float*)d_in[2];
  const float* Wk = (const float*)d_in[3];
  const float* bk = (const float*)d_in[4];
  const float* Wv = (const float*)d_in[5];
  const float* bv = (const float*)d_in[6];
  const float* Wo = (const float*)d_in[7];
  const float* bo = (const float*)d_in[8];

  static bool attr_set = false;
  if (!attr_set) {
    hipFuncSetAttribute((const void*)gemm_kernel,
                        hipFuncAttributeMaxDynamicSharedMemorySize, 131072);
    attr_set = true;
  }

  char* ws = (char*)d_ws;
  u16* Xb  = (u16*)(ws);                    // 64 MB
  u16* Wqb = (u16*)(ws + 67108864);         // 8 MB each (Wq,Wk,Wv,Wo contiguous)
  u16* Qp  = (u16*)(ws + 100663296);        // 64 MB paged
  u16* Kp  = (u16*)(ws + 167772160);        // 64 MB paged
  u16* Vt  = (u16*)(ws + 234881024);        // 64 MB transposed-paged
  u16* Cb  = (u16*)(ws + 301989888);        // 64 MB ctx bf16 (B,S,HID)
  u16* Wkb = Wqb + 4194304;
  u16* Wvb = Wqb + 8388608;
  u16* Wob = Wqb + 12582912;

  cvt_kernel<<<32768, 256, 0, stream>>>(X, Xb, 8388608);
  cvtw_kernel<<<dim3(4096, 4), 256, 0, stream>>>(Wq, Wk, Wv, Wo, Wqb, 1048576);

  gemm_kernel<<<dim3(512, 3), 512, 131072, stream>>>(
      Xb, Wqb, Wkb, Wvb, bq, bk, bv, (void*)Qp, (void*)Kp, (void*)Vt, 0, 0, 1);

  attn_kernel<<<1024, 1024, 0, stream>>>(Qp, Kp, Vt, Cb);

  gemm_kernel<<<dim3(512, 1), 512, 131072, stream>>>(
      Cb, Wob, Wob, Wob, bo, bo, bo, d_out, d_out, d_out, 2, 2, 2);
}